// Round 4
// baseline (76.854 us; speedup 1.0000x reference)
//
#include <hip/hip_runtime.h>

// Fused cascaded-biquad IIR (DF2T) via linear state-space chunking.
// ONE kernel, one block per batch row (512 blocks x 512 threads):
//   - each thread owns a 64-step chunk, held in 16 float4 registers
//   - stage-in: rolling 2-tile prefetch -> LDS transpose -> regs (coalesced)
//   - wave 0 builds M_d = (A^64)^(2^d) in-register via __shfl (no barriers)
//   - phase A: chunk final state from zero init
//   - block-local Kogge-Stone affine scan over 512 chunks (9 levels)
//   - phase B: replay from exact initial state, stage-out via LDS (coalesced)
// No workspace, no inter-block communication.

namespace {
constexpr int NS     = 4;              // biquad sections
constexpr int BATCH  = 512;
constexpr int TLEN   = 32768;          // 2^15
constexpr int NSTATE = 2 * NS;         // 8
constexpr int NTHR   = 512;            // threads/block = chunks/batch
constexpr int L      = TLEN / NTHR;    // 64 steps per chunk
constexpr int LQ     = L / 4;          // 16 float4 per chunk
constexpr int LOG2L  = 6;              // log2(L)
constexpr int LOG2P  = 9;              // scan levels over 512 chunks
constexpr int NTILE  = 4;              // stage tiles per phase
constexpr int TQ     = LQ / NTILE;     // 4 float4 per chunk per tile
constexpr int RS     = TQ + 1;         // LDS row stride (float4) -> 8-group banks
}

__device__ __forceinline__ void load_coefs(const float* __restrict__ bc,
                                           const float* __restrict__ ac,
                                           float b0[NS], float b1[NS], float b2[NS],
                                           float a1[NS], float a2[NS]) {
#pragma unroll
  for (int k = 0; k < NS; ++k) {
    b0[k] = bc[3 * k];
    b1[k] = bc[3 * k + 1];
    b2[k] = bc[3 * k + 2];
    a1[k] = ac[2 * k];
    a2[k] = ac[2 * k + 1];
  }
}

// One time-step through the 4-section cascade (matches reference exactly).
__device__ __forceinline__ float step_cascade(float sig,
                                              const float b0[NS], const float b1[NS],
                                              const float b2[NS], const float a1[NS],
                                              const float a2[NS],
                                              float s1[NS], float s2[NS]) {
#pragma unroll
  for (int k = 0; k < NS; ++k) {
    float y = fmaf(b0[k], sig, s1[k]);
    s1[k]   = fmaf(-a1[k], y, fmaf(b1[k], sig, s2[k]));
    s2[k]   = fmaf(-a2[k], y, b2[k] * sig);
    sig = y;
  }
  return sig;
}

__global__ __launch_bounds__(NTHR, 4) void k_fused(const float* __restrict__ x,
                                                   const float* __restrict__ bc,
                                                   const float* __restrict__ ac,
                                                   float* __restrict__ out) {
  __shared__ float4 lin[NTHR * RS];        // 40 KiB transpose tile
  __shared__ float  W[NTHR][NSTATE + 1];   // 18 KiB scan buffer (stride 9: conflict-free)
  __shared__ float  Ms[LOG2P][64];         // 2.25 KiB matrix powers

  const int t  = threadIdx.x;
  const int bi = blockIdx.x;

  float b0[NS], b1[NS], b2[NS], a1[NS], a2[NS];
  load_coefs(bc, ac, b0, b1, b2, a1, a2);

  const float4* __restrict__ gsrc =
      reinterpret_cast<const float4*>(x) + (size_t)bi * (TLEN / 4);
  float4* __restrict__ gdst =
      reinterpret_cast<float4*>(out) + (size_t)bi * (TLEN / 4);

  // Per-(tile,q) global float4 index: 64B-segment coalesced, every line fully used.
  const int gbase = 16 * (t >> 2) + (t & 3);  // + 2048*q + 4*tile

  // Rolling 2-tile prefetch: issue tile0+tile1 loads immediately (8 in flight).
  float4 stg[2][TQ];
#pragma unroll
  for (int q = 0; q < TQ; ++q) stg[0][q] = gsrc[gbase + 2048 * q + 4 * 0];
#pragma unroll
  for (int q = 0; q < TQ; ++q) stg[1][q] = gsrc[gbase + 2048 * q + 4 * 1];

  // Wave 0: build Ms[d] = (A^L)^(2^d) entirely in registers via __shfl.
  // Lane = r*8+c holds element (r,c). No block barriers inside (wave-local).
  if (t < 64) {
    const int r = t >> 3, c = t & 7;
    float p1[NS] = {0.f, 0.f, 0.f, 0.f};
    float p2[NS] = {0.f, 0.f, 0.f, 0.f};
    if (c & 1) p2[c >> 1] = 1.0f; else p1[c >> 1] = 1.0f;
    (void)step_cascade(0.0f, b0, b1, b2, a1, a2, p1, p2);
    float m = (r & 1) ? p2[r >> 1] : p1[r >> 1];  // A element (r,c)
    for (int it = 0; it < LOG2L + LOG2P - 1; ++it) {  // 14 squarings
      float acc = 0.0f;
#pragma unroll
      for (int k = 0; k < NSTATE; ++k)
        acc = fmaf(__shfl(m, r * 8 + k), __shfl(m, k * 8 + c), acc);
      m = acc;
      if (it >= LOG2L - 1) Ms[it - (LOG2L - 1)][t] = m;  // A^64 ... A^(64*256)
    }
  }

  float s1[NS] = {0.f, 0.f, 0.f, 0.f};
  float s2[NS] = {0.f, 0.f, 0.f, 0.f};
  float4 data[LQ];  // this thread's chunk (x now, y later) — static indices only

  // ---------------- Phase A: chunk final state from zero init ----------------
#pragma unroll
  for (int tile = 0; tile < NTILE; ++tile) {
    if (tile) __syncthreads();  // prior tile's reads complete before overwrite
#pragma unroll
    for (int q = 0; q < TQ; ++q)
      lin[((t >> 2) + 128 * q) * RS + (t & 3)] = stg[tile & 1][q];
    if (tile + 2 < NTILE) {  // prefetch tile+2 into the buffer just drained
#pragma unroll
      for (int q = 0; q < TQ; ++q)
        stg[tile & 1][q] = gsrc[gbase + 2048 * q + 4 * (tile + 2)];
    }
    __syncthreads();
#pragma unroll
    for (int q = 0; q < TQ; ++q) {
      const float4 u = lin[t * RS + q];
      data[tile * TQ + q] = u;
      (void)step_cascade(u.x, b0, b1, b2, a1, a2, s1, s2);
      (void)step_cascade(u.y, b0, b1, b2, a1, a2, s1, s2);
      (void)step_cascade(u.z, b0, b1, b2, a1, a2, s1, s2);
      (void)step_cascade(u.w, b0, b1, b2, a1, a2, s1, s2);
    }
  }

  // ---------------- Block-local Kogge-Stone affine scan ----------------
  // w_i <- M_d * w_{i-2^d} + w_i  (w = inclusive state-after-chunk-i)
  float w[NSTATE];
#pragma unroll
  for (int k = 0; k < NS; ++k) { w[2 * k] = s1[k]; w[2 * k + 1] = s2[k]; }

  for (int d = 0; d < LOG2P; ++d) {
#pragma unroll
    for (int r = 0; r < NSTATE; ++r) W[t][r] = w[r];
    __syncthreads();
    if (t >= (1 << d)) {
      const int src = t - (1 << d);
      float prev[NSTATE];
#pragma unroll
      for (int r = 0; r < NSTATE; ++r) prev[r] = W[src][r];
#pragma unroll
      for (int r = 0; r < NSTATE; ++r) {
        float acc = w[r];
#pragma unroll
        for (int k = 0; k < NSTATE; ++k)
          acc = fmaf(Ms[d][r * 8 + k], prev[k], acc);  // broadcast read: free
        w[r] = acc;
      }
    }
    __syncthreads();
  }

  // Exclusive shift: s_init(i) = (i==0 ? 0 : w_{i-1})
#pragma unroll
  for (int r = 0; r < NSTATE; ++r) W[t][r] = w[r];
  __syncthreads();
  {
    const int src = (t == 0) ? 0 : t - 1;  // avoid OOB; result masked below
#pragma unroll
    for (int k = 0; k < NS; ++k) {
      s1[k] = (t == 0) ? 0.0f : W[src][2 * k];
      s2[k] = (t == 0) ? 0.0f : W[src][2 * k + 1];
    }
  }

  // ---------------- Phase B: replay from exact init, stage out ----------------
#pragma unroll
  for (int tile = 0; tile < NTILE; ++tile) {
    if (tile) __syncthreads();  // prior tile's coalesced reads complete
#pragma unroll
    for (int q = 0; q < TQ; ++q) {
      const float4 u = data[tile * TQ + q];
      float4 y;
      y.x = step_cascade(u.x, b0, b1, b2, a1, a2, s1, s2);
      y.y = step_cascade(u.y, b0, b1, b2, a1, a2, s1, s2);
      y.z = step_cascade(u.z, b0, b1, b2, a1, a2, s1, s2);
      y.w = step_cascade(u.w, b0, b1, b2, a1, a2, s1, s2);
      lin[t * RS + q] = y;
    }
    __syncthreads();
#pragma unroll
    for (int q = 0; q < TQ; ++q)
      gdst[gbase + 2048 * q + 4 * tile] =
          lin[((t >> 2) + 128 * q) * RS + (t & 3)];
  }
}

extern "C" void kernel_launch(void* const* d_in, const int* in_sizes, int n_in,
                              void* d_out, int out_size, void* d_ws, size_t ws_size,
                              hipStream_t stream) {
  const float* x  = (const float*)d_in[0];  // (B, T, 1)
  const float* bc = (const float*)d_in[1];  // (NS, 3)
  const float* ac = (const float*)d_in[2];  // (NS, 2)
  float* out = (float*)d_out;               // (B, T, 1)

  k_fused<<<BATCH, NTHR, 0, stream>>>(x, bc, ac, out);
}